// Round 1
// baseline (9563.532 us; speedup 1.0000x reference)
//
#include <hip/hip_runtime.h>

// Problem constants (from reference): x[8,25,256,256] conv w[100,25,9,9] VALID -> out[8,100,248,248]
#define NB   8
#define NC   25
#define NH   256
#define NW   256
#define NOC  100
#define KH_  9
#define KW_  9
#define OH   248
#define OW   248

#define TW   32            // output tile width  (threads x)
#define TH   8             // output tile height (threads y)
#define LDSW (TW + KW_ - 1)  // 40
#define LDSH (TH + KH_ - 1)  // 16
#define OCC  25            // output channels per register chunk (4 chunks)

__global__ __launch_bounds__(256)
void conv_fp32_direct(const float* __restrict__ x,
                      const float* __restrict__ w,
                      const float* __restrict__ bias,
                      float* __restrict__ out) {
    // 25 channels x 16 x 40 floats = 64000 B of LDS -> 2 blocks/CU
    __shared__ float tile[NC][LDSH * LDSW];

    const int tid = threadIdx.x;
    const int tx  = tid & 31;
    const int ty  = tid >> 5;
    const int x0  = blockIdx.x * TW;   // 0..224
    const int y0  = blockIdx.y * TH;   // 0..240
    const int b   = blockIdx.z;

    // ---- stage all 25 channel tiles (with right-edge clamp; clamped cols feed
    //      only out-of-range outputs which are never stored) ----
    const float* xb = x + (size_t)b * NC * NH * NW;
    for (int i = tid; i < NC * LDSH * LDSW; i += 256) {
        int c  = i / (LDSH * LDSW);
        int r  = (i - c * (LDSH * LDSW)) / LDSW;
        int cc = i - c * (LDSH * LDSW) - r * LDSW;
        int gy = y0 + r;                    // <= 255 always (y0<=240, r<=15)
        int gx = x0 + cc; if (gx > NW - 1) gx = NW - 1;
        tile[c][r * LDSW + cc] = xb[(c * NH + gy) * NW + gx];
    }
    __syncthreads();

    const int ox = x0 + tx;
    const int oy = y0 + ty;
    const bool valid = (ox < OW);

    for (int occ = 0; occ < NOC; occ += OCC) {
        float acc[OCC];
        #pragma unroll
        for (int oc = 0; oc < OCC; ++oc) acc[oc] = bias[occ + oc];

        for (int c = 0; c < NC; ++c) {
            const float* tc = &tile[c][ty * LDSW + tx];
            // weight base for this (occ, c): w[oc][c][ky][kx], oc-stride = NC*81
            const float* wc = w + (size_t)occ * (NC * KH_ * KW_) + c * (KH_ * KW_);
            #pragma unroll 1
            for (int ky = 0; ky < KH_; ++ky) {
                float xv[KW_];
                #pragma unroll
                for (int kx = 0; kx < KW_; ++kx)
                    xv[kx] = tc[ky * LDSW + kx];
                const float* wcy = wc + ky * KW_;
                #pragma unroll
                for (int oc = 0; oc < OCC; ++oc) {
                    float a = acc[oc];
                    #pragma unroll
                    for (int kx = 0; kx < KW_; ++kx)
                        a = fmaf(xv[kx], wcy[(size_t)oc * (NC * KH_ * KW_) + kx], a);
                    acc[oc] = a;
                }
            }
        }

        if (valid) {
            #pragma unroll
            for (int oc = 0; oc < OCC; ++oc)
                out[(((size_t)b * NOC + occ + oc) * OH + oy) * OW + ox] = acc[oc];
        }
    }
}

extern "C" void kernel_launch(void* const* d_in, const int* in_sizes, int n_in,
                              void* d_out, int out_size, void* d_ws, size_t ws_size,
                              hipStream_t stream) {
    const float* pic  = (const float*)d_in[0];
    const float* wgt  = (const float*)d_in[1];
    const float* bias = (const float*)d_in[2];
    float* out        = (float*)d_out;

    dim3 grid((OW + TW - 1) / TW, OH / TH, NB);  // 8 x 31 x 8 = 1984 blocks
    dim3 block(256);
    hipLaunchKernelGGL(conv_fp32_direct, grid, block, 0, stream, pic, wgt, bias, out);
}

// Round 2
// 622.451 us; speedup vs baseline: 15.3643x; 15.3643x over previous
//
#include <hip/hip_runtime.h>

// x[8,25,256,256] (fp32) conv w[100,25,9,9] VALID -> out[8,100,248,248] (fp32)
// Implicit GEMM: D[oc][n] = sum_{ky,kx} W[oc][c32] * Xshift[c32][n], bf16 MFMA 16x16x32.

#define NB   8
#define NC   25
#define C32  32
#define NH   256
#define NW   256
#define NOC  100
#define MT   7      // 7 M-tiles of 16 -> 112 (oc padded)
#define KH_  9
#define KW_  9
#define OH   248
#define OW   248

typedef __attribute__((ext_vector_type(8))) short bf16x8;
typedef __attribute__((ext_vector_type(4))) float f32x4;

// ws layout: [wf: 81*7*64*8 bf16 = 580,608 B][pad to 1 MB][xt: 8*256*256*32 bf16 = 33,554,432 B]
#define WF_ELEMS   (KH_ * KW_ * MT * 64 * 8)          // 290,304
#define XT_OFFSET  (1 << 20)                           // 1 MiB, generous alignment
#define XT_ELEMS   (NB * NH * NW * C32)                // 16,777,216

__device__ __forceinline__ unsigned short f2bf(float f) {
    unsigned u = __float_as_uint(f);
    return (unsigned short)((u + 0x7FFFu + ((u >> 16) & 1u)) >> 16);
}

// ---- prep 1: weights -> A-fragment order ----
// wf[((ky*9+kx)*7 + mt)*64 + lane][j]  (j=0..7)
// A[m][k]: m = oc = mt*16 + (lane&15), k = c = (lane>>4)*8 + j
__global__ void prep_wf(const float* __restrict__ w, short* __restrict__ wf) {
    int idx = blockIdx.x * 256 + threadIdx.x;
    if (idx >= WF_ELEMS) return;
    int j    = idx & 7;
    int lane = (idx >> 3) & 63;
    int rest = idx >> 9;          // (ky*9+kx)*7 + mt
    int mt   = rest % MT;
    int p    = rest / MT;         // ky*9+kx
    int ky   = p / KW_;
    int kx   = p % KW_;
    int oc   = mt * 16 + (lane & 15);
    int c    = (lane >> 4) * 8 + j;
    float v = 0.0f;
    if (oc < NOC && c < NC)
        v = w[(((size_t)oc * NC + c) * KH_ + ky) * KW_ + kx];
    wf[idx] = (short)f2bf(v);
}

// ---- prep 2: x[b][c][y][x] fp32 -> xt[b][y][x][c32] bf16 (c 25..31 = 0) ----
__global__ void prep_xt(const float* __restrict__ x, short* __restrict__ xt) {
    int b  = blockIdx.x >> 8;
    int y  = blockIdx.x & 255;
    int xc = threadIdx.x;          // 0..255
    unsigned short v[C32];
    #pragma unroll
    for (int c = 0; c < NC; ++c)
        v[c] = f2bf(x[(((size_t)b * NC + c) * NH + y) * NW + xc]);
    #pragma unroll
    for (int c = NC; c < C32; ++c) v[c] = 0;
    short* dst = xt + (((size_t)b * NH + y) * NW + xc) * C32;
    #pragma unroll
    for (int i = 0; i < 4; ++i)
        ((int4*)dst)[i] = ((const int4*)v)[i];
}

// ---- main: one block = one output row (b, oy); 4 waves x N=64; M=112 ----
__global__ __launch_bounds__(256, 2)
void conv_mfma(const short* __restrict__ wf, const short* __restrict__ xt,
               const float* __restrict__ bias, float* __restrict__ out) {
    const int oy   = blockIdx.x;
    const int b    = blockIdx.y;
    const int lane = threadIdx.x & 63;
    const int wv   = threadIdx.x >> 6;
    const int n    = lane & 15;
    const int quad = lane >> 4;
    const int x0w  = wv * 64;

    f32x4 acc[MT][4];
    #pragma unroll
    for (int mt = 0; mt < MT; ++mt)
        #pragma unroll
        for (int nt = 0; nt < 4; ++nt)
            acc[mt][nt] = (f32x4){0.f, 0.f, 0.f, 0.f};

    const short* xtb = xt + ((size_t)b * NH) * NW * C32;

    for (int ky = 0; ky < KH_; ++ky) {
        const short* xrow = xtb + (size_t)(oy + ky) * NW * C32;
        #pragma unroll 3
        for (int kx = 0; kx < KW_; ++kx) {
            // A fragments: contiguous 1 KB per (ky,kx,mt), lane-indexed 16 B
            const short* wbase = wf + ((size_t)((ky * KW_ + kx) * MT) * 64 + lane) * 8;
            bf16x8 a[MT];
            #pragma unroll
            for (int mt = 0; mt < MT; ++mt)
                a[mt] = *(const bf16x8*)(wbase + (size_t)mt * 64 * 8);
            #pragma unroll
            for (int nt = 0; nt < 4; ++nt) {
                int xcol = x0w + nt * 16 + n + kx;
                if (xcol > NW - 1) xcol = NW - 1;   // only affects masked cols
                bf16x8 bfr = *(const bf16x8*)(xrow + (size_t)xcol * C32 + quad * 8);
                #pragma unroll
                for (int mt = 0; mt < MT; ++mt)
                    acc[mt][nt] = __builtin_amdgcn_mfma_f32_16x16x32_bf16(
                        a[mt], bfr, acc[mt][nt], 0, 0, 0);
            }
        }
    }

    // epilogue: C/D layout col = lane&15 (ox), row = quad*4 + r (oc)
    #pragma unroll
    for (int mt = 0; mt < MT; ++mt) {
        #pragma unroll
        for (int nt = 0; nt < 4; ++nt) {
            int ox = x0w + nt * 16 + n;
            if (ox >= OW) continue;
            #pragma unroll
            for (int r = 0; r < 4; ++r) {
                int oc = mt * 16 + quad * 4 + r;
                if (oc < NOC)
                    out[(((size_t)b * NOC + oc) * OH + oy) * OW + ox] =
                        acc[mt][nt][r] + bias[oc];
            }
        }
    }
}

extern "C" void kernel_launch(void* const* d_in, const int* in_sizes, int n_in,
                              void* d_out, int out_size, void* d_ws, size_t ws_size,
                              hipStream_t stream) {
    const float* pic  = (const float*)d_in[0];
    const float* wgt  = (const float*)d_in[1];
    const float* bias = (const float*)d_in[2];
    float* out        = (float*)d_out;

    short* wf = (short*)d_ws;
    short* xt = (short*)((char*)d_ws + XT_OFFSET);

    hipLaunchKernelGGL(prep_wf, dim3((WF_ELEMS + 255) / 256), dim3(256), 0, stream, wgt, wf);
    hipLaunchKernelGGL(prep_xt, dim3(NB * NH), dim3(NW), 0, stream, pic, xt);
    hipLaunchKernelGGL(conv_mfma, dim3(OH, NB), dim3(256), 0, stream, wf, xt, bias, out);
}

// Round 3
// 531.618 us; speedup vs baseline: 17.9895x; 1.1709x over previous
//
#include <hip/hip_runtime.h>

// x[8,25,256,256] (fp32) conv w[100,25,9,9] VALID -> out[8,100,248,248] (fp32)
// Implicit GEMM on bf16 MFMA 16x16x32, software-pipelined 81-step K-loop.

#define NB   8
#define NC   25
#define C32  32
#define NH   256
#define NW   256
#define NOC  100
#define MT   7      // 7 M-tiles of 16 -> 112 (oc padded)
#define KH_  9
#define KW_  9
#define OH   248
#define OW   248

typedef __attribute__((ext_vector_type(8))) short bf16x8;
typedef __attribute__((ext_vector_type(4))) float f32x4;

// ws layout: [wf: 81*7*64*8 bf16][pad to 1 MiB][xt: 8*256*256*32 bf16 = 33.5 MB]
#define WF_ELEMS   (KH_ * KW_ * MT * 64 * 8)          // 290,304
#define XT_OFFSET  (1 << 20)

__device__ __forceinline__ unsigned short f2bf(float f) {
    unsigned u = __float_as_uint(f);
    return (unsigned short)((u + 0x7FFFu + ((u >> 16) & 1u)) >> 16);
}

// ---- prep 1: weights -> A-fragment order ----
// wf[(p*7 + mt)*64 + lane][j], p = ky*9+kx; A[m][k]: m = oc = mt*16+(lane&15),
// k = c = (lane>>4)*8 + j
__global__ void prep_wf(const float* __restrict__ w, short* __restrict__ wf) {
    int idx = blockIdx.x * 256 + threadIdx.x;
    if (idx >= WF_ELEMS) return;
    int j    = idx & 7;
    int lane = (idx >> 3) & 63;
    int rest = idx >> 9;
    int mt   = rest % MT;
    int p    = rest / MT;
    int ky   = p / KW_;
    int kx   = p % KW_;
    int oc   = mt * 16 + (lane & 15);
    int c    = (lane >> 4) * 8 + j;
    float v = 0.0f;
    if (oc < NOC && c < NC)
        v = w[(((size_t)oc * NC + c) * KH_ + ky) * KW_ + kx];
    wf[idx] = (short)f2bf(v);
}

// ---- prep 2: x[b][c][y][x] fp32 -> xt[b][y][x][c32] bf16, via LDS transpose ----
__global__ __launch_bounds__(256)
void prep_xt(const float* __restrict__ x, short* __restrict__ xt) {
    __shared__ short row[NC][NW];          // 12.8 KB
    const int b = blockIdx.x >> 8;
    const int y = blockIdx.x & 255;
    const float* src = x + ((size_t)b * NC) * NH * NW + (size_t)y * NW;

    // coalesced float4 loads: 25 rows x 64 float4
    for (int i = threadIdx.x; i < NC * 64; i += 256) {
        int c  = i >> 6;
        int xq = (i & 63) << 2;
        float4 v = *(const float4*)(src + (size_t)c * NH * NW + xq);
        unsigned short s[4] = { f2bf(v.x), f2bf(v.y), f2bf(v.z), f2bf(v.w) };
        *(unsigned long long*)&row[c][xq] = *(const unsigned long long*)s;
    }
    __syncthreads();

    const int xc = threadIdx.x;
    unsigned short v[C32];
    #pragma unroll
    for (int c = 0; c < NC; ++c) v[c] = (unsigned short)row[c][xc];
    #pragma unroll
    for (int c = NC; c < C32; ++c) v[c] = 0;
    short* dst = xt + (((size_t)b * NH + y) * NW + xc) * C32;
    #pragma unroll
    for (int i = 0; i < 4; ++i)
        ((int4*)dst)[i] = ((const int4*)v)[i];
}

// ---- fragment loader for pipeline step p = ky*9+kx (p compile-time under unroll) ----
__device__ __forceinline__ void load_frags(int p, const short* __restrict__ wf,
                                           const short* __restrict__ xrow0,
                                           int lane, int n, int quad, int x0w,
                                           bf16x8* a, bf16x8* bv) {
    const int ky = p / 9, kx = p % 9;
    const short* wbase = wf + (((size_t)p * MT) * 64 + lane) * 8;
    #pragma unroll
    for (int mt = 0; mt < MT; ++mt)
        a[mt] = *(const bf16x8*)(wbase + (size_t)mt * 64 * 8);
    const short* xrow = xrow0 + (size_t)ky * NW * C32;
    #pragma unroll
    for (int nt = 0; nt < 4; ++nt) {
        int xcol = x0w + nt * 16 + n + kx;
        if (xcol > NW - 1) xcol = NW - 1;      // only feeds masked-out cols
        bv[nt] = *(const bf16x8*)(xrow + (size_t)xcol * C32 + quad * 8);
    }
}

// ---- main: one block = one output row (b, oy); 4 waves x N=64; M=112 ----
__global__ __launch_bounds__(256, 2)
void conv_mfma(const short* __restrict__ wf, const short* __restrict__ xt,
               const float* __restrict__ bias, float* __restrict__ out) {
    const int bx   = blockIdx.x;                 // 0..247
    const int oy   = (bx & 7) * 31 + (bx >> 3);  // XCD-aware: consecutive oy per XCD
    const int b    = blockIdx.y;
    const int lane = threadIdx.x & 63;
    const int wv   = threadIdx.x >> 6;
    const int n    = lane & 15;
    const int quad = lane >> 4;
    const int x0w  = wv * 64;

    f32x4 acc[MT][4];
    #pragma unroll
    for (int mt = 0; mt < MT; ++mt)
        #pragma unroll
        for (int nt = 0; nt < 4; ++nt)
            acc[mt][nt] = (f32x4){0.f, 0.f, 0.f, 0.f};

    const short* xrow0 = xt + (((size_t)b * NH) + oy) * NW * C32;

    bf16x8 a[2][MT];
    bf16x8 bv[2][4];
    load_frags(0, wf, xrow0, lane, n, quad, x0w, a[0], bv[0]);

    #pragma unroll
    for (int p = 0; p < 81; ++p) {
        const int cur = p & 1;
        if (p < 80)
            load_frags(p + 1, wf, xrow0, lane, n, quad, x0w, a[cur ^ 1], bv[cur ^ 1]);
        #pragma unroll
        for (int nt = 0; nt < 4; ++nt)
            #pragma unroll
            for (int mt = 0; mt < MT; ++mt)
                acc[mt][nt] = __builtin_amdgcn_mfma_f32_16x16x32_bf16(
                    a[cur][mt], bv[cur][nt], acc[mt][nt], 0, 0, 0);
    }

    // epilogue: C/D layout col = lane&15 (ox), row = quad*4 + r (oc)
    #pragma unroll
    for (int mt = 0; mt < MT; ++mt) {
        #pragma unroll
        for (int nt = 0; nt < 4; ++nt) {
            int ox = x0w + nt * 16 + n;
            if (ox >= OW) continue;
            #pragma unroll
            for (int r = 0; r < 4; ++r) {
                int oc = mt * 16 + quad * 4 + r;
                if (oc < NOC)
                    out[(((size_t)b * NOC + oc) * OH + oy) * OW + ox] =
                        acc[mt][nt][r] + bias[oc];
            }
        }
    }
}

extern "C" void kernel_launch(void* const* d_in, const int* in_sizes, int n_in,
                              void* d_out, int out_size, void* d_ws, size_t ws_size,
                              hipStream_t stream) {
    const float* pic  = (const float*)d_in[0];
    const float* wgt  = (const float*)d_in[1];
    const float* bias = (const float*)d_in[2];
    float* out        = (float*)d_out;

    short* wf = (short*)d_ws;
    short* xt = (short*)((char*)d_ws + XT_OFFSET);

    hipLaunchKernelGGL(prep_wf, dim3((WF_ELEMS + 255) / 256), dim3(256), 0, stream, wgt, wf);
    hipLaunchKernelGGL(prep_xt, dim3(NB * NH), dim3(256), 0, stream, pic, xt);
    hipLaunchKernelGGL(conv_mfma, dim3(OH, NB), dim3(256), 0, stream, wf, xt, bias, out);
}